// Round 6
// baseline (123.305 us; speedup 1.0000x reference)
//
#include <hip/hip_runtime.h>

// HaloAttention with the lucidrains masking bug faithfully replicated:
// in-bounds keys get -FLT_MAX, so
//   * interior blocks -> uniform attention = 16x16 box-mean of v
//   * border blocks   -> attention only on zero-padded keys -> output exactly 0
// Collapse: out_block = mean16x16(x) @ (w_kv[:,512:] @ w_out) + b_out (interior),
//           0 (border). q / w_q / rel_* are dead inputs.
//
// Dispatch 1 (prep): blocks 0..511 compute 16x16 window means for 4 channel
//   planes each. Only coarse-tile rows/cols 1..14 are ever used by interior
//   windows -> edge tiles are skipped (23% fetch cut). Blocks 512..639
//   compose W = w_kv_v @ w_out.
// Dispatch 2 (out): block = (32-channel group g, block row bi, batch b).
//   Phase 1: matvec outv[c][bj] into LDS via float4 W loads with 4-way k-split.
//   Phase 2: stream the 8x64x32 strip with coalesced non-temporal float4 stores.

typedef float nfloat4 __attribute__((ext_vector_type(4)));  // native vec for nontemporal builtins

__global__ __launch_bounds__(256)
void halo_prep_kernel(const float* __restrict__ x,
                      const float* __restrict__ w_kv,
                      const float* __restrict__ w_out,
                      float* __restrict__ W,
                      float* __restrict__ means) {
    const int t = threadIdx.x;
    if (blockIdx.x < 512) {
        // ---- window means for 4 (b, c) planes ----
        const int b  = blockIdx.x >> 6;
        const int c0 = (blockIdx.x & 63) * 4;
        __shared__ float ts[4][256];  // per-plane 16x16 coarse 4x4-tile sums
        const int ti = t >> 4, tj = t & 15;
        // only tile rows/cols 1..14 feed interior windows (rows 4..59)
        const bool need = (ti >= 1) & (ti <= 14) & (tj >= 1) & (tj <= 14);
#pragma unroll
        for (int q = 0; q < 4; ++q) {
            float s = 0.f;
            if (need) {
                const float* tp = x + ((size_t)(b * 256 + c0 + q)) * 4096
                                    + (size_t)(ti * 4) * 64 + tj * 4;
#pragma unroll
                for (int r = 0; r < 4; ++r) {
                    nfloat4 a = __builtin_nontemporal_load(
                        (const nfloat4*)(tp + (size_t)r * 64));
                    s += (a.x + a.y) + (a.z + a.w);
                }
            }
            ts[q][t] = s;
        }
        __syncthreads();
        if (t < 144) {
            // interior block (bi,bj) = (wi+1, wj+1); window top row bi*8-4
            // -> tile row 2*bi-1, spans 4 tile rows/cols (all within 1..14)
            const int q  = t / 36;
            const int w  = t - q * 36;
            const int wi = w / 6, wj = w - wi * 6;
            const int tr = 2 * wi + 1, tc = 2 * wj + 1;
            float acc = 0.f;
#pragma unroll
            for (int di = 0; di < 4; ++di)
#pragma unroll
                for (int dj = 0; dj < 4; ++dj)
                    acc += ts[q][(tr + di) * 16 + (tc + dj)];
            means[((size_t)b * 36 + w) * 256 + (c0 + q)] = acc * (1.f / 256.f);
        }
    } else {
        // ---- compose W rows c0, c0+1: W[c][c2] = sum_j w_kv[c][512+j]*w_out[j][c2] ----
        const int c0 = (blockIdx.x - 512) * 2;
        const float* kv0 = w_kv + (size_t)c0 * 1024 + 512;
        const float* kv1 = kv0 + 1024;
        float a0 = 0.f, a1 = 0.f;
#pragma unroll 8
        for (int j = 0; j < 512; ++j) {
            const float wo = w_out[(size_t)j * 256 + t];  // coalesced over t
            a0 = fmaf(kv0[j], wo, a0);                    // kv*: wg-uniform scalar loads
            a1 = fmaf(kv1[j], wo, a1);
        }
        W[(size_t)c0 * 256 + t] = a0;
        W[((size_t)c0 + 1) * 256 + t] = a1;
    }
}

__global__ __launch_bounds__(256)
void halo_out_kernel(const float* __restrict__ W,
                     const float* __restrict__ means,
                     const float* __restrict__ b_out,
                     float* __restrict__ out) {
    const int g  = blockIdx.x;   // channel group 0..7 (32 channels)
    const int bi = blockIdx.y;   // block row 0..7
    const int b  = blockIdx.z;   // batch
    const int t  = threadIdx.x;
    const bool bi_int = (bi >= 1) & (bi <= 6);

    __shared__ float m_lds[8][256];   // means rows per bj (0 at border bj)
    __shared__ float4 psum4[256];     // [(bj*8+q)*4 + sub]
    __shared__ float outv[32 * 9];    // [c_local][bj], stride 9 avoids conflicts

    if (bi_int) {  // wg-uniform branch: barriers inside are legal
        // stage means rows (bj=1..6 real, bj=0,7 zero)
        {
            const int row = t >> 5;
            const int col0 = t & 31;
            const float* mrow = (row >= 1 && row <= 6)
                ? &means[((size_t)b * 36 + (size_t)(bi - 1) * 6 + (row - 1)) * 256]
                : nullptr;
#pragma unroll
            for (int kk = col0; kk < 256; kk += 32)
                m_lds[row][kk] = mrow ? mrow[kk] : 0.f;
        }
        __syncthreads();

        // matvec: thread (bj = t>>5, sub = (t>>3)&3, q = t&7)
        // computes partial over k in [sub*64, sub*64+64) for channels cb..cb+3
        {
            const int bj  = t >> 5;
            const int sub = (t >> 3) & 3;
            const int q   = t & 7;
            const int cb  = g * 32 + q * 4;    // 16B-aligned
            const float* mr = m_lds[bj];
            const int k0 = sub * 64;
            float4 a = make_float4(0.f, 0.f, 0.f, 0.f);
#pragma unroll 4
            for (int k = k0; k < k0 + 64; ++k) {
                const float4 w4 = *(const float4*)&W[(size_t)k * 256 + cb];
                const float mm = mr[k];
                a.x = fmaf(mm, w4.x, a.x);
                a.y = fmaf(mm, w4.y, a.y);
                a.z = fmaf(mm, w4.z, a.z);
                a.w = fmaf(mm, w4.w, a.w);
            }
            psum4[(bj * 8 + q) * 4 + sub] = a;
        }
        __syncthreads();

        // reduce 4 k-partials -> outv[c][bj], add bias, zero border bj
        {
            const int bj = t >> 5;
            const int cl = t & 31;
            const int q2 = cl >> 2, ch = cl & 3;
            const float* ps = (const float*)psum4;
            float v = 0.f;
#pragma unroll
            for (int s = 0; s < 4; ++s)
                v += ps[((bj * 8 + q2) * 4 + s) * 4 + ch];
            const bool bj_int = (bj >= 1) & (bj <= 6);
            outv[cl * 9 + bj] = bj_int ? v + b_out[g * 32 + cl] : 0.f;
        }
        __syncthreads();
    }

    // phase 2: stream the strip out[b][g*32..+32][bi*8..+8][0..64]
    // each wave writes 1 KB fully contiguous, non-temporal (write-once stream)
    float* base = out + ((size_t)(b * 256 + g * 32)) * 4096 + (size_t)(bi * 8) * 64;
#pragma unroll
    for (int i = 0; i < 16; ++i) {
        const int idx = i * 256 + t;     // float4 index in the 64 KB strip
        const int cl2 = idx >> 7;        // 128 float4 per channel
        const int rem = idx & 127;       // y*16 + x4
        const int x4  = rem & 15;
        const float v = bi_int ? outv[cl2 * 9 + (x4 >> 1)] : 0.f;
        nfloat4 v4 = {v, v, v, v};
        __builtin_nontemporal_store(v4,
            (nfloat4*)(base + (size_t)cl2 * 4096 + (size_t)rem * 4));
    }
}

extern "C" void kernel_launch(void* const* d_in, const int* in_sizes, int n_in,
                              void* d_out, int out_size, void* d_ws, size_t ws_size,
                              hipStream_t stream) {
    // setup_inputs order: x, w_q, w_kv, w_out, b_out, rel_height, rel_width
    const float* x     = (const float*)d_in[0];
    const float* w_kv  = (const float*)d_in[2];
    const float* w_out = (const float*)d_in[3];
    const float* b_out = (const float*)d_in[4];
    float* W     = (float*)d_ws;            // 256*256 floats = 256 KiB
    float* means = W + 256 * 256;           // 8*36*256 floats = 288 KiB

    halo_prep_kernel<<<512 + 128, 256, 0, stream>>>(x, w_kv, w_out, W, means);
    halo_out_kernel<<<dim3(8, 8, 8), 256, 0, stream>>>(W, means, b_out, (float*)d_out);
}